// Round 1
// baseline (3954.371 us; speedup 1.0000x reference)
//
#include <hip/hip_runtime.h>
#include <hip/hip_bf16.h>

typedef float   f32x4_t  __attribute__((ext_vector_type(4)));
typedef __bf16  bf16x8_t __attribute__((ext_vector_type(8)));
typedef int     i32x4_t  __attribute__((ext_vector_type(4)));

#define N_ROWS   16384
#define N_COLS   1000
#define N_COLS_P 1024
#define N_DIM    512
#define N_ITER   100
#define FUSE_BLOCKS 512
#define ROWS_PER_BLOCK (N_ROWS / FUSE_BLOCKS)   /* 32 */
#define ROWS_PER_WAVE  (ROWS_PER_BLOCK / 4)     /* 8  */

__device__ __forceinline__ unsigned short f2bf(float f) {
    unsigned int u = __builtin_bit_cast(unsigned int, f);
    u += 0x7FFFu + ((u >> 16) & 1u);            // RNE round to bf16
    return (unsigned short)(u >> 16);
}

// ---------------------------------------------------------------------------
// GEMM: dot = F[16384x512] @ T[1000x512]^T ; K = exp(-2*s/(1-s)), s = 2*dot.
// Writes K (f32) into d_out, and per-(rowblock) column partial sums for KtU0.
// 128x128 tile, 4 waves (2x2), 16x16x32 bf16 MFMA, BK=64.
// ---------------------------------------------------------------------------
__launch_bounds__(256)
__global__ void k_gemm(const float* __restrict__ F, const float* __restrict__ T,
                       float* __restrict__ Kout, float* __restrict__ cpart)
{
    __shared__ unsigned short lA[128 * 72];
    __shared__ unsigned short lB[128 * 72];
    __shared__ float cs_lds[4 * 64];

    const int bm = blockIdx.x;            // 0..127
    const int bn = blockIdx.y;            // 0..7
    const int m0 = bm << 7;
    const int n0 = bn << 7;
    const int t  = threadIdx.x;
    const int lane = t & 63;
    const int wid  = t >> 6;
    const int wr = wid >> 1;              // 0..1
    const int wc = wid & 1;               // 0..1

    f32x4_t acc[4][4];
#pragma unroll
    for (int a = 0; a < 4; ++a)
#pragma unroll
        for (int b = 0; b < 4; ++b)
            acc[a][b] = (f32x4_t){0.f, 0.f, 0.f, 0.f};

    const int srow = t >> 4;              // 0..15
    const int scol = (t & 15) << 2;       // 0..60

    for (int kt = 0; kt < N_DIM; kt += 64) {
#pragma unroll
        for (int r = 0; r < 8; ++r) {
            const int rr = srow + (r << 4);
            const float4 av = *(const float4*)(F + (size_t)(m0 + rr) * N_DIM + kt + scol);
            ushort4 a4; a4.x = f2bf(av.x); a4.y = f2bf(av.y); a4.z = f2bf(av.z); a4.w = f2bf(av.w);
            *(ushort4*)(&lA[rr * 72 + scol]) = a4;
            const int gn = n0 + rr;
            float4 bv = make_float4(0.f, 0.f, 0.f, 0.f);
            if (gn < N_COLS) bv = *(const float4*)(T + (size_t)gn * N_DIM + kt + scol);
            ushort4 b4; b4.x = f2bf(bv.x); b4.y = f2bf(bv.y); b4.z = f2bf(bv.z); b4.w = f2bf(bv.w);
            *(ushort4*)(&lB[rr * 72 + scol]) = b4;
        }
        __syncthreads();
#pragma unroll
        for (int ks = 0; ks < 2; ++ks) {
            bf16x8_t afr[4], bfr[4];
#pragma unroll
            for (int mf = 0; mf < 4; ++mf) {
                const int r = (wr << 6) + (mf << 4) + (lane & 15);
                const int off = r * 72 + (ks << 5) + ((lane >> 4) << 3);
                afr[mf] = __builtin_bit_cast(bf16x8_t, *(const i32x4_t*)(&lA[off]));
            }
#pragma unroll
            for (int nf = 0; nf < 4; ++nf) {
                const int r = (wc << 6) + (nf << 4) + (lane & 15);
                const int off = r * 72 + (ks << 5) + ((lane >> 4) << 3);
                bfr[nf] = __builtin_bit_cast(bf16x8_t, *(const i32x4_t*)(&lB[off]));
            }
#pragma unroll
            for (int mf = 0; mf < 4; ++mf)
#pragma unroll
                for (int nf = 0; nf < 4; ++nf)
                    acc[mf][nf] = __builtin_amdgcn_mfma_f32_16x16x32_bf16(
                        afr[mf], bfr[nf], acc[mf][nf], 0, 0, 0);
        }
        __syncthreads();
    }

    // Epilogue: K = exp(-2*M), M = s/(1-s), s = 2*dot.  C/D layout:
    // col = lane&15, row = (lane>>4)*4 + j   [guide §3, m89-verified]
    float csum[4] = {0.f, 0.f, 0.f, 0.f};
#pragma unroll
    for (int mf = 0; mf < 4; ++mf) {
#pragma unroll
        for (int nf = 0; nf < 4; ++nf) {
#pragma unroll
            for (int j = 0; j < 4; ++j) {
                const float d = acc[mf][nf][j];
                const float s = 2.f * d;
                const float M = s / (1.f - s);
                const float kv = __expf(-2.f * M);
                const int grow = m0 + (wr << 6) + (mf << 4) + ((lane >> 4) << 2) + j;
                const int gcol = n0 + (wc << 6) + (nf << 4) + (lane & 15);
                if (gcol < N_COLS) Kout[(size_t)grow * N_COLS + gcol] = kv;
                csum[nf] += kv;
            }
        }
    }
#pragma unroll
    for (int nf = 0; nf < 4; ++nf) {
        csum[nf] += __shfl_xor(csum[nf], 16);
        csum[nf] += __shfl_xor(csum[nf], 32);
    }
    if (lane < 16) {
#pragma unroll
        for (int nf = 0; nf < 4; ++nf)
            cs_lds[wid * 64 + (nf << 4) + lane] = csum[nf];
    }
    __syncthreads();
    if (t < 128) {
        const int cw = t >> 6;
        const int c6 = t & 63;
        cpart[(size_t)bm * N_COLS_P + n0 + t] =
            cs_lds[cw * 64 + c6] + cs_lds[(cw + 2) * 64 + c6];
    }
}

// ---------------------------------------------------------------------------
// init: KtU0 = colsum(K)/16384 (u0 = 1/16384), v_com = 1/1000, flags reset.
// flags: [0]=done  [1]=u_sel (2 = initial uniform u0)  [2]=bad
// ---------------------------------------------------------------------------
__launch_bounds__(128)
__global__ void k_init(const float* __restrict__ cpart, float* __restrict__ KtU0,
                       float* __restrict__ v_com, float* __restrict__ err2slots,
                       int* __restrict__ flags)
{
    const int j = blockIdx.x * 128 + threadIdx.x;
    if (j < N_COLS) {
        float s = 0.f;
        for (int p = 0; p < 128; ++p) s += cpart[(size_t)p * N_COLS_P + j];
        KtU0[j] = s * (1.f / 16384.f);
        v_com[j] = 1.f / 1000.f;
    }
    if (blockIdx.x == 0 && threadIdx.x == 0) { flags[0] = 0; flags[1] = 2; flags[2] = 0; }
    if (blockIdx.x == 0 && threadIdx.x < 8) err2slots[threadIdx.x] = 0.f;
}

// ---------------------------------------------------------------------------
// FUSE: one pass over K per iteration.
//   v_new = b / KtU_cur            (per-block, in LDS)
//   u_new[i] = 1 / (K[i,:] @ v_new)  -> u_out
//   partials[blk][j] = sum_i K[i][j] * u_new[i]   (register col accumulators)
// ---------------------------------------------------------------------------
__launch_bounds__(256)
__global__ void k_fuse(const float* __restrict__ Kmat, const float* __restrict__ ratios,
                       const float* __restrict__ KtU_cur, float* __restrict__ u_out,
                       float* __restrict__ partials, int* __restrict__ flags)
{
    if (*(volatile int*)&flags[0]) return;
    __shared__ float vnew[N_COLS_P];
    __shared__ float wp[4][N_COLS_P];
    const int t = threadIdx.x;
    for (int j = t; j < N_COLS_P; j += 256) {
        float v = 0.f;
        if (j < N_COLS) v = (ratios[j] * 16384.f) / KtU_cur[j];
        vnew[j] = v;
    }
    __syncthreads();

    const int lane = t & 63;
    const int wid  = t >> 6;
    float creg[16];
#pragma unroll
    for (int e = 0; e < 16; ++e) creg[e] = 0.f;

    const int jl = lane << 2;
    const bool ok3 = (768 + jl + 3) < N_COLS;      // lane < 58
    const float4 v0 = *(const float4*)(vnew + jl);
    const float4 v1 = *(const float4*)(vnew + 256 + jl);
    const float4 v2 = *(const float4*)(vnew + 512 + jl);
    const float4 v3 = ok3 ? *(const float4*)(vnew + 768 + jl) : make_float4(0,0,0,0);

    const int base_row = blockIdx.x * ROWS_PER_BLOCK + wid * ROWS_PER_WAVE;
    for (int r = 0; r < ROWS_PER_WAVE; ++r) {
        const int i = base_row + r;
        const float* krow = Kmat + (size_t)i * N_COLS;
        const float4 k0 = *(const float4*)(krow + jl);
        const float4 k1 = *(const float4*)(krow + 256 + jl);
        const float4 k2 = *(const float4*)(krow + 512 + jl);
        const float4 k3 = ok3 ? *(const float4*)(krow + 768 + jl) : make_float4(0,0,0,0);
        float dot = k0.x*v0.x + k0.y*v0.y + k0.z*v0.z + k0.w*v0.w
                  + k1.x*v1.x + k1.y*v1.y + k1.z*v1.z + k1.w*v1.w
                  + k2.x*v2.x + k2.y*v2.y + k2.z*v2.z + k2.w*v2.w
                  + k3.x*v3.x + k3.y*v3.y + k3.z*v3.z + k3.w*v3.w;
#pragma unroll
        for (int s = 32; s; s >>= 1) dot += __shfl_xor(dot, s);
        const float u = 1.f / dot;
        if (lane == 0) {
            u_out[i] = u;
            if (!isfinite(u)) atomicOr(&flags[2], 1);
        }
        creg[0]  += k0.x * u; creg[1]  += k0.y * u; creg[2]  += k0.z * u; creg[3]  += k0.w * u;
        creg[4]  += k1.x * u; creg[5]  += k1.y * u; creg[6]  += k1.z * u; creg[7]  += k1.w * u;
        creg[8]  += k2.x * u; creg[9]  += k2.y * u; creg[10] += k2.z * u; creg[11] += k2.w * u;
        creg[12] += k3.x * u; creg[13] += k3.y * u; creg[14] += k3.z * u; creg[15] += k3.w * u;
    }
#pragma unroll
    for (int c = 0; c < 4; ++c)
        *(float4*)(&wp[wid][(c << 8) + jl]) =
            make_float4(creg[c*4], creg[c*4+1], creg[c*4+2], creg[c*4+3]);
    __syncthreads();
    for (int j = t; j < N_COLS_P; j += 256)
        partials[(size_t)blockIdx.x * N_COLS_P + j] = wp[0][j] + wp[1][j] + wp[2][j] + wp[3][j];
}

// ---------------------------------------------------------------------------
// R1: KtU_next[j] = sum_p partials[p][j]; err contribution (tmp2-b)^2; checks.
// ---------------------------------------------------------------------------
__launch_bounds__(128)
__global__ void k_r1(const float* __restrict__ partials, const float* __restrict__ KtU_cur,
                     float* __restrict__ KtU_next, const float* __restrict__ ratios,
                     float* __restrict__ err2slots, int* __restrict__ flags)
{
    if (*(volatile int*)&flags[0]) return;
    const int t = threadIdx.x;
    const int j = blockIdx.x * 128 + t;
    float errc = 0.f;
    if (j < N_COLS) {
        float s = 0.f;
        for (int p = 0; p < FUSE_BLOCKS; ++p) s += partials[(size_t)p * N_COLS_P + j];
        KtU_next[j] = s;
        const float kc = KtU_cur[j];
        const float b  = ratios[j] * 16384.f;
        const float vn = b / kc;
        if (kc == 0.f || !isfinite(vn)) atomicOr(&flags[2], 1);
        const float t2 = s * vn;
        const float d  = t2 - b;
        errc = d * d;
    }
#pragma unroll
    for (int s = 32; s; s >>= 1) errc += __shfl_xor(errc, s);
    __shared__ float w2[2];
    if ((t & 63) == 0) w2[t >> 6] = errc;
    __syncthreads();
    if (t == 0) err2slots[blockIdx.x] = w2[0] + w2[1];
}

// ---------------------------------------------------------------------------
// R2: done/bad/converged logic; commit v (and u via u_sel=parity) if live.
// ---------------------------------------------------------------------------
__launch_bounds__(256)
__global__ void k_r2(const float* __restrict__ KtU_cur, const float* __restrict__ ratios,
                     float* __restrict__ v_com, float* __restrict__ err2slots,
                     int* __restrict__ flags, int ii, int parity)
{
    if (*(volatile int*)&flags[0]) return;
    __shared__ int s_bad, s_conv;
    const int t = threadIdx.x;
    if (t == 0) {
        float e2 = 0.f;
        for (int i = 0; i < 8; ++i) e2 += err2slots[i];
        s_bad = flags[2];
        s_conv = (((ii % 10) == 0) && (e2 < 1e-18f)) ? 1 : 0;
    }
    __syncthreads();
    if (s_bad) {
        if (t == 0) { flags[0] = 1; flags[2] = 0; }
        return;
    }
    for (int j = t; j < N_COLS; j += 256)
        v_com[j] = (ratios[j] * 16384.f) / KtU_cur[j];
    if (t < 8) err2slots[t] = 0.f;
    if (t == 0) {
        flags[1] = parity;
        flags[2] = 0;
        if (s_conv) flags[0] = 1;
    }
}

// ---------------------------------------------------------------------------
// PLAN: in-place d_out[i][j] = u[i] * K[i][j] * v[j]
// ---------------------------------------------------------------------------
__launch_bounds__(256)
__global__ void k_plan(float* __restrict__ Kmat, const float* __restrict__ v_com,
                       const float* __restrict__ u_t0, const float* __restrict__ u_t1,
                       const int* __restrict__ flags)
{
    const int idx4 = blockIdx.x * 256 + threadIdx.x;   // float4 index, row stride 250
    const int row = idx4 / 250;
    const int col = (idx4 - row * 250) << 2;
    const int us = flags[1];
    float u;
    if (us == 2)       u = 1.f / 16384.f;
    else if (us == 0)  u = u_t0[row];
    else               u = u_t1[row];
    float4 k = *(float4*)(Kmat + ((size_t)idx4 << 2));
    const float4 vv = *(const float4*)(v_com + col);
    k.x *= u * vv.x; k.y *= u * vv.y; k.z *= u * vv.z; k.w *= u * vv.w;
    *(float4*)(Kmat + ((size_t)idx4 << 2)) = k;
}

extern "C" void kernel_launch(void* const* d_in, const int* in_sizes, int n_in,
                              void* d_out, int out_size, void* d_ws, size_t ws_size,
                              hipStream_t stream)
{
    const float* F      = (const float*)d_in[0];
    const float* T      = (const float*)d_in[1];
    const float* ratios = (const float*)d_in[2];
    float* Kmat = (float*)d_out;

    // workspace layout (floats)
    float* ws        = (float*)d_ws;
    float* partials  = ws;                                  // 512*1024
    float* ktu       = partials + (size_t)FUSE_BLOCKS * N_COLS_P; // 2*1024
    float* utmp      = ktu + 2 * N_COLS_P;                  // 2*16384
    float* vcom      = utmp + 2 * N_ROWS;                   // 1024
    float* err2slots = vcom + N_COLS_P;                     // 8
    int*   flags     = (int*)(err2slots + 8);               // 3 ints
    const size_t need_bytes = ((size_t)FUSE_BLOCKS * N_COLS_P + 2 * N_COLS_P +
                               2 * N_ROWS + N_COLS_P + 8) * sizeof(float) + 4 * sizeof(int);
    if (ws_size < need_bytes) return;  // fail loudly (output stays poisoned)

    k_gemm<<<dim3(128, 8), 256, 0, stream>>>(F, T, Kmat, partials);
    k_init<<<8, 128, 0, stream>>>(partials, ktu, vcom, err2slots, flags);
    for (int ii = 0; ii < N_ITER; ++ii) {
        const int p = ii & 1;
        k_fuse<<<FUSE_BLOCKS, 256, 0, stream>>>(Kmat, ratios, ktu + p * N_COLS_P,
                                                utmp + (size_t)p * N_ROWS, partials, flags);
        k_r1<<<8, 128, 0, stream>>>(partials, ktu + p * N_COLS_P, ktu + (1 - p) * N_COLS_P,
                                    ratios, err2slots, flags);
        k_r2<<<1, 256, 0, stream>>>(ktu + p * N_COLS_P, ratios, vcom, err2slots, flags, ii, p);
    }
    k_plan<<<16000, 256, 0, stream>>>(Kmat, vcom, utmp, utmp + N_ROWS, flags);
}

// Round 2
// 2221.871 us; speedup vs baseline: 1.7797x; 1.7797x over previous
//
#include <hip/hip_runtime.h>
#include <hip/hip_bf16.h>

typedef float   f32x4_t  __attribute__((ext_vector_type(4)));
typedef __bf16  bf16x8_t __attribute__((ext_vector_type(8)));
typedef int     i32x4_t  __attribute__((ext_vector_type(4)));

#define N_ROWS   16384
#define N_COLS   1000
#define N_COLS_P 1024
#define N_DIM    512
#define N_ITER   100
#define FUSE_BLOCKS 512
#define R12_BLOCKS  16

__device__ __forceinline__ unsigned short f2bf(float f) {
    unsigned int u = __builtin_bit_cast(unsigned int, f);
    u += 0x7FFFu + ((u >> 16) & 1u);            // RNE round to bf16
    return (unsigned short)(u >> 16);
}

// ---------------------------------------------------------------------------
// GEMM pass: dot = F[16384x512] @ T[1000x512]^T ; K = exp(-2*s/(1-s)), s=2*dot.
// MODE 0: write K as bf16 (row stride 1024, zero-padded) into d_out, plus
//         per-rowblock column sums (for KtU0).
// MODE 1: final plan: out[i][j] = u[i] * K[i][j] * v[j]  (f32, stride 1000).
// 128x128 tile, 4 waves (2x2), 16x16x32 bf16 MFMA, BK=64.
// ---------------------------------------------------------------------------
template <int MODE>
__launch_bounds__(256)
__global__ void k_gemm(const float* __restrict__ F, const float* __restrict__ T,
                       void* __restrict__ Kout, float* __restrict__ cpart,
                       const float* __restrict__ v_com, const float* __restrict__ u_both,
                       const int* __restrict__ flags)
{
    __shared__ unsigned short lA[128 * 72];
    __shared__ unsigned short lB[128 * 72];
    __shared__ float cs_lds[4 * 64];

    const int bm = blockIdx.x;            // 0..127
    const int bn = blockIdx.y;            // 0..7
    const int m0 = bm << 7;
    const int n0 = bn << 7;
    const int t  = threadIdx.x;
    const int lane = t & 63;
    const int wid  = t >> 6;
    const int wr = wid >> 1;              // 0..1
    const int wc = wid & 1;               // 0..1

    f32x4_t acc[4][4];
#pragma unroll
    for (int a = 0; a < 4; ++a)
#pragma unroll
        for (int b = 0; b < 4; ++b)
            acc[a][b] = (f32x4_t){0.f, 0.f, 0.f, 0.f};

    const int srow = t >> 4;              // 0..15
    const int scol = (t & 15) << 2;       // 0..60

    for (int kt = 0; kt < N_DIM; kt += 64) {
#pragma unroll
        for (int r = 0; r < 8; ++r) {
            const int rr = srow + (r << 4);
            const float4 av = *(const float4*)(F + (size_t)(m0 + rr) * N_DIM + kt + scol);
            ushort4 a4; a4.x = f2bf(av.x); a4.y = f2bf(av.y); a4.z = f2bf(av.z); a4.w = f2bf(av.w);
            *(ushort4*)(&lA[rr * 72 + scol]) = a4;
            const int gn = n0 + rr;
            float4 bv = make_float4(0.f, 0.f, 0.f, 0.f);
            if (gn < N_COLS) bv = *(const float4*)(T + (size_t)gn * N_DIM + kt + scol);
            ushort4 b4; b4.x = f2bf(bv.x); b4.y = f2bf(bv.y); b4.z = f2bf(bv.z); b4.w = f2bf(bv.w);
            *(ushort4*)(&lB[rr * 72 + scol]) = b4;
        }
        __syncthreads();
#pragma unroll
        for (int ks = 0; ks < 2; ++ks) {
            bf16x8_t afr[4], bfr[4];
#pragma unroll
            for (int mf = 0; mf < 4; ++mf) {
                const int r = (wr << 6) + (mf << 4) + (lane & 15);
                const int off = r * 72 + (ks << 5) + ((lane >> 4) << 3);
                afr[mf] = __builtin_bit_cast(bf16x8_t, *(const i32x4_t*)(&lA[off]));
            }
#pragma unroll
            for (int nf = 0; nf < 4; ++nf) {
                const int r = (wc << 6) + (nf << 4) + (lane & 15);
                const int off = r * 72 + (ks << 5) + ((lane >> 4) << 3);
                bfr[nf] = __builtin_bit_cast(bf16x8_t, *(const i32x4_t*)(&lB[off]));
            }
#pragma unroll
            for (int mf = 0; mf < 4; ++mf)
#pragma unroll
                for (int nf = 0; nf < 4; ++nf)
                    acc[mf][nf] = __builtin_amdgcn_mfma_f32_16x16x32_bf16(
                        afr[mf], bfr[nf], acc[mf][nf], 0, 0, 0);
        }
        __syncthreads();
    }

    // C/D layout: col = lane&15, row = (lane>>4)*4 + j  [m89-verified]
    int usel = 2;
    if (MODE == 1) usel = flags[1];
    float csum[4] = {0.f, 0.f, 0.f, 0.f};
#pragma unroll
    for (int mf = 0; mf < 4; ++mf) {
#pragma unroll
        for (int nf = 0; nf < 4; ++nf) {
#pragma unroll
            for (int j = 0; j < 4; ++j) {
                const float d = acc[mf][nf][j];
                const float s = 2.f * d;
                const float M = s / (1.f - s);
                const float kv = __expf(-2.f * M);
                const int grow = m0 + (wr << 6) + (mf << 4) + ((lane >> 4) << 2) + j;
                const int gcol = n0 + (wc << 6) + (nf << 4) + (lane & 15);
                if (MODE == 0) {
                    ((unsigned short*)Kout)[(size_t)grow * N_COLS_P + gcol] =
                        (gcol < N_COLS) ? f2bf(kv) : (unsigned short)0;
                    csum[nf] += kv;
                } else {
                    if (gcol < N_COLS) {
                        const float u = (usel == 2) ? (1.f / 16384.f)
                                                    : u_both[(size_t)usel * N_ROWS + grow];
                        ((float*)Kout)[(size_t)grow * N_COLS + gcol] = u * kv * v_com[gcol];
                    }
                }
            }
        }
    }
    if (MODE == 0) {
#pragma unroll
        for (int nf = 0; nf < 4; ++nf) {
            csum[nf] += __shfl_xor(csum[nf], 16);
            csum[nf] += __shfl_xor(csum[nf], 32);
        }
        if (lane < 16) {
#pragma unroll
            for (int nf = 0; nf < 4; ++nf)
                cs_lds[wid * 64 + (nf << 4) + lane] = csum[nf];
        }
        __syncthreads();
        if (t < 128) {
            const int cw = t >> 6;
            const int c6 = t & 63;
            cpart[(size_t)bm * N_COLS_P + n0 + t] =
                cs_lds[cw * 64 + c6] + cs_lds[(cw + 2) * 64 + c6];
        }
    }
}

// ---------------------------------------------------------------------------
// init: KtU0 = colsum(K)/16384 (u0=1/16384), v_com = 1/1000, flags reset.
// flags: [0]=done [1]=u_sel (2=uniform u0) [2]=bad [3]=r12 completion counter
// ---------------------------------------------------------------------------
__launch_bounds__(128)
__global__ void k_init(const float* __restrict__ cpart, float* __restrict__ KtU0,
                       float* __restrict__ v_com, float* __restrict__ err2slots,
                       int* __restrict__ flags)
{
    const int j = blockIdx.x * 128 + threadIdx.x;
    if (j < N_COLS) {
        float s = 0.f;
        for (int p = 0; p < 128; ++p) s += cpart[(size_t)p * N_COLS_P + j];
        KtU0[j] = s * (1.f / 16384.f);
        v_com[j] = 1.f / 1000.f;
    }
    if (blockIdx.x == 0 && threadIdx.x == 0) {
        flags[0] = 0; flags[1] = 2; flags[2] = 0; flags[3] = 0;
    }
    if (blockIdx.x == 0 && threadIdx.x < R12_BLOCKS) err2slots[threadIdx.x] = 0.f;
}

// ---------------------------------------------------------------------------
// FUSE: one pass over bf16 K per iteration.
//   v_new = b / KtU_cur  (per-block LDS, then register-cached per lane)
//   u_new[i] = 1 / (K[i,:] @ v_new)           -> u_out
//   partials[blk][j] = sum_i K[i][j]*u_new[i] (register col accumulators)
// 512 blocks x 256 thr, 32 rows/block, 8 rows/wave, 16 cols/lane (bf16x16=32B).
// ---------------------------------------------------------------------------
__launch_bounds__(256)
__global__ void k_fuse(const unsigned short* __restrict__ Kb, const float* __restrict__ ratios,
                       const float* __restrict__ KtU_cur, float* __restrict__ u_out,
                       float* __restrict__ partials, int* __restrict__ flags)
{
    if (*(volatile int*)&flags[0]) return;
    __shared__ float vnew[N_COLS_P];
    __shared__ float wp[4][N_COLS_P];
    const int t = threadIdx.x;
    const int lane = t & 63;
    const int wid  = t >> 6;
    for (int j = t; j < N_COLS_P; j += 256) {
        float v = 0.f;
        if (j < N_COLS) v = (ratios[j] * 16384.f) / KtU_cur[j];
        vnew[j] = v;
    }
    __syncthreads();

    const int c0 = lane << 4;             // this lane's 16 columns
    float vr[16];
#pragma unroll
    for (int e = 0; e < 16; ++e) vr[e] = vnew[c0 + e];
    float creg[16];
#pragma unroll
    for (int e = 0; e < 16; ++e) creg[e] = 0.f;

    const int base_row = blockIdx.x * 32 + wid * 8;
    const unsigned short* rowp = Kb + (size_t)base_row * N_COLS_P + c0;
#pragma unroll
    for (int r = 0; r < 8; ++r) {
        const i32x4_t d0 = *(const i32x4_t*)(rowp);
        const i32x4_t d1 = *(const i32x4_t*)(rowp + 8);
        rowp += N_COLS_P;
        float kv[16];
#pragma unroll
        for (int q = 0; q < 4; ++q) {
            kv[2*q]     = __builtin_bit_cast(float, (unsigned)d0[q] << 16);
            kv[2*q+1]   = __builtin_bit_cast(float, (unsigned)d0[q] & 0xFFFF0000u);
            kv[8+2*q]   = __builtin_bit_cast(float, (unsigned)d1[q] << 16);
            kv[8+2*q+1] = __builtin_bit_cast(float, (unsigned)d1[q] & 0xFFFF0000u);
        }
        float p0 = kv[0]*vr[0], p1 = kv[1]*vr[1], p2 = kv[2]*vr[2], p3 = kv[3]*vr[3];
#pragma unroll
        for (int e = 4; e < 16; e += 4) {
            p0 += kv[e]*vr[e]; p1 += kv[e+1]*vr[e+1];
            p2 += kv[e+2]*vr[e+2]; p3 += kv[e+3]*vr[e+3];
        }
        float dot = (p0 + p1) + (p2 + p3);
#pragma unroll
        for (int s = 32; s; s >>= 1) dot += __shfl_xor(dot, s);
        const float u = 1.f / dot;
        if (lane == 0) {
            u_out[base_row + r] = u;
            if (!isfinite(u)) atomicOr(&flags[2], 1);
        }
#pragma unroll
        for (int e = 0; e < 16; ++e) creg[e] += kv[e] * u;
    }
#pragma unroll
    for (int q = 0; q < 4; ++q)
        *(float4*)(&wp[wid][c0 + (q << 2)]) =
            make_float4(creg[4*q], creg[4*q+1], creg[4*q+2], creg[4*q+3]);
    __syncthreads();
    {
        const int j4 = t << 2;
        const float4 A = *(const float4*)(&wp[0][j4]);
        const float4 B = *(const float4*)(&wp[1][j4]);
        const float4 C = *(const float4*)(&wp[2][j4]);
        const float4 D = *(const float4*)(&wp[3][j4]);
        *(float4*)(&partials[(size_t)blockIdx.x * N_COLS_P + j4]) =
            make_float4(A.x+B.x+C.x+D.x, A.y+B.y+C.y+D.y,
                        A.z+B.z+C.z+D.z, A.w+B.w+C.w+D.w);
    }
}

// ---------------------------------------------------------------------------
// R12: KtU_next[j] = sum_p partials[p][j]; err = ||KtU_next*v_new - b||^2;
// last block (completion counter) commits v_com + flags (done/bad/converged).
// 16 blocks x 256 thr: 64 cols/block, 4-way split over the 512 partials.
// ---------------------------------------------------------------------------
__launch_bounds__(256)
__global__ void k_r12(const float* __restrict__ partials, const float* __restrict__ KtU_cur,
                      float* __restrict__ KtU_next, const float* __restrict__ ratios,
                      float* __restrict__ v_com, float* __restrict__ err2slots,
                      int* __restrict__ flags, int ii, int parity)
{
    if (*(volatile int*)&flags[0]) return;
    const int t = threadIdx.x;
    const int jl = t & 63;
    const int q  = t >> 6;                // 0..3
    const int j  = blockIdx.x * 64 + jl;
    float s = 0.f;
    const float* pp = partials + (size_t)(q * 128) * N_COLS_P + j;
#pragma unroll 8
    for (int p = 0; p < 128; ++p) { s += *pp; pp += N_COLS_P; }
    __shared__ float red[4][64];
    __shared__ int s_last;
    red[q][jl] = s;
    __syncthreads();
    if (t < 64) {
        const int jj = blockIdx.x * 64 + t;
        float errc = 0.f;
        if (jj < N_COLS) {
            const float sum = red[0][t] + red[1][t] + red[2][t] + red[3][t];
            KtU_next[jj] = sum;
            const float b  = ratios[jj] * 16384.f;
            const float kc = KtU_cur[jj];
            const float vn = b / kc;
            if (kc == 0.f || !isfinite(vn)) atomicOr(&flags[2], 1);
            const float d = sum * vn - b;
            errc = d * d;
        }
#pragma unroll
        for (int sh = 32; sh; sh >>= 1) errc += __shfl_xor(errc, sh);
        if (t == 0) {
            err2slots[blockIdx.x] = errc;
            __threadfence();
            s_last = (atomicAdd(&flags[3], 1) == R12_BLOCKS - 1) ? 1 : 0;
        }
    }
    __syncthreads();
    if (s_last) {
        __threadfence();                  // acquire: see other blocks' writes
        const int bad = *(volatile int*)&flags[2];
        if (!bad) {
            for (int jj = t; jj < N_COLS; jj += 256)
                v_com[jj] = (ratios[jj] * 16384.f) / KtU_cur[jj];
        }
        if (t == 0) {
            float e2 = 0.f;
            for (int b2 = 0; b2 < R12_BLOCKS; ++b2) e2 += err2slots[b2];
            flags[3] = 0;                 // reset counter for next iteration
            if (bad) { flags[0] = 1; flags[2] = 0; }
            else {
                flags[1] = parity;
                if ((ii % 10) == 0 && e2 < 1e-18f) flags[0] = 1;
            }
        }
    }
}

extern "C" void kernel_launch(void* const* d_in, const int* in_sizes, int n_in,
                              void* d_out, int out_size, void* d_ws, size_t ws_size,
                              hipStream_t stream)
{
    const float* F      = (const float*)d_in[0];
    const float* T      = (const float*)d_in[1];
    const float* ratios = (const float*)d_in[2];
    float* out = (float*)d_out;
    unsigned short* Kb = (unsigned short*)d_out;   // bf16 K, stride 1024, 33.5MB

    // workspace layout (floats); gemm colsum partials alias fuse partials
    float* ws        = (float*)d_ws;
    float* partials  = ws;                                   // 512*1024
    float* ktu       = partials + (size_t)FUSE_BLOCKS * N_COLS_P; // 2*1024
    float* utmp      = ktu + 2 * N_COLS_P;                   // 2*16384
    float* vcom      = utmp + 2 * N_ROWS;                    // 1024
    float* err2slots = vcom + N_COLS_P;                      // 16
    int*   flags     = (int*)(err2slots + R12_BLOCKS);       // 4 ints
    const size_t need_bytes = ((size_t)FUSE_BLOCKS * N_COLS_P + 2 * N_COLS_P +
                               2 * N_ROWS + N_COLS_P + R12_BLOCKS) * sizeof(float)
                              + 4 * sizeof(int);
    if (ws_size < need_bytes) return;  // fail loudly (output stays poisoned)

    k_gemm<0><<<dim3(128, 8), 256, 0, stream>>>(F, T, Kb, partials, nullptr, nullptr, flags);
    k_init<<<8, 128, 0, stream>>>(partials, ktu, vcom, err2slots, flags);
    for (int ii = 0; ii < N_ITER; ++ii) {
        const int p = ii & 1;
        k_fuse<<<FUSE_BLOCKS, 256, 0, stream>>>(Kb, ratios, ktu + p * N_COLS_P,
                                                utmp + (size_t)p * N_ROWS, partials, flags);
        k_r12<<<R12_BLOCKS, 256, 0, stream>>>(partials, ktu + p * N_COLS_P,
                                              ktu + (1 - p) * N_COLS_P, ratios, vcom,
                                              err2slots, flags, ii, p);
    }
    k_gemm<1><<<dim3(128, 8), 256, 0, stream>>>(F, T, out, nullptr, vcom, utmp, flags);
}